// Round 4
// baseline (859.437 us; speedup 1.0000x reference)
//
#include <hip/hip_runtime.h>

// RelativeLearnableAttention — MI355X (round 9)
// B=4 N=2048 DIM=256 H=8 D=32, scale = 1/16.
// Contract (established empirically R1–R6): inputs f32, mask int32,
// d_out = FLOAT32 (out [4,2048,256] ++ attn [4,8,2048,2048]).
// Internals: bf16 MFMA pipeline (kprep converts once); final stores f32.
// R9: kattn occupancy doubled. Diagnosis: latency-bound (MfmaUtil 5%, VALU 17%,
// HBM 23%) at 44% occupancy (grid 1024x4waves = half the machine). ILP-based
// prefetch failed: compiler sank prefetches to fit 56 VGPR. Lever = TLP.
//  - 512-thread blocks: 8 waves = 4 i-subtiles x 2 j-halves; each wave sweeps
//    16 j-tiles. Partial l and PV combined through LDS (aliased onto pbuf,
//    2x __syncthreads). 4 blocks/CU x 8 waves = 32 waves/CU = 100% occupancy.
//  - __launch_bounds__(512,8) caps VGPR at 64 (body fits ~56).
//  - no explicit prefetch arrays (dead weight at this register budget).

typedef short bf16x8 __attribute__((ext_vector_type(8)));
typedef float f32x4 __attribute__((ext_vector_type(4)));

static __device__ __forceinline__ unsigned short f2b(float f) {
    union { float f; unsigned int u; } x; x.f = f;
    unsigned int r = x.u + 0x7fffu + ((x.u >> 16) & 1u);   // RNE
    return (unsigned short)(r >> 16);
}

static __device__ __forceinline__ float exp2_fast(float x) {
    float r;
    asm("v_exp_f32 %0, %1" : "=v"(r) : "v"(x));   // D = 2^S0
    return r;
}

// ---------------------------------------------------------------------------
// Prep: f32->bf16 of w, r; transpose+convert Wqkv/Wr/Wout; mask -> mw[b][i]
// (left-pad True). 12 MB traffic.
__global__ __launch_bounds__(256) void kprep(
    const float* __restrict__ w, const float* __restrict__ r,
    const float* __restrict__ Wqkv, const float* __restrict__ Wr,
    const float* __restrict__ Wout, const int* __restrict__ amask,
    unsigned short* __restrict__ wb, unsigned short* __restrict__ rb,
    unsigned short* __restrict__ WqkvT, unsigned short* __restrict__ WrT,
    unsigned short* __restrict__ WoutT, int* __restrict__ mw)
{
    int o = blockIdx.x * 256 + threadIdx.x;
    if (o < 2097152) { wb[o] = f2b(w[o]); return; }
    o -= 2097152;
    if (o < 524288) { rb[o] = f2b(r[o]); return; }
    o -= 524288;
    if (o < 196608) { int n = o >> 8, k = o & 255; WqkvT[o] = f2b(Wqkv[k * 768 + n]); return; }
    o -= 196608;
    if (o < 65536) { int n = o >> 8, k = o & 255; WrT[o] = f2b(Wr[k * 256 + n]); return; }
    o -= 65536;
    if (o < 65536) { int n = o >> 8, k = o & 255; WoutT[o] = f2b(Wout[k * 256 + n]); return; }
    o -= 65536;
    {   // o in [0, 8192)
        const int b = o >> 11, i = o & 2047;
        mw[o] = (i == 0) ? 1 : (amask[b * 2047 + i - 1] != 0);
    }
}

// ---------------------------------------------------------------------------
// QKV GEMM: [8192x256] @ [256x768]; epilogue splits q/k/v, adds f32 biases to q,
// writes q1=(q+r_w_bias)*CS, q2=(q+r_r_bias)*CS (CS = scale*log2e folded so the
// attention kernel can use raw v_exp_f32), k as [bh][n][32], v transposed [bh][32][n].
__global__ __launch_bounds__(256) void kqkv(
    const unsigned short* __restrict__ w,      // [8192][256] bf16
    const unsigned short* __restrict__ WqkvT,  // [768][256] bf16
    const float* __restrict__ rwb,             // [256] f32 (h*32+d)
    const float* __restrict__ rrb,             // [256] f32
    unsigned short* __restrict__ q1w,          // [32][2048][32]
    unsigned short* __restrict__ q2w,
    unsigned short* __restrict__ kw,           // [32][2048][32]
    unsigned short* __restrict__ vTw)          // [32][32][2048]
{
    const int m0 = blockIdx.x * 64;
    const int n0 = blockIdx.y * 64;
    const int tid = threadIdx.x;
    const int wid = tid >> 6, lane = tid & 63;
    const int l16 = lane & 15, quad = lane >> 4;

    const float CS = 0.09016844f;   // (1/16) * log2(e)

    f32x4 acc[4] = {};
    const unsigned short* arow = w + (m0 + wid * 16 + l16) * 256 + quad * 8;
    for (int kc = 0; kc < 8; ++kc) {
        bf16x8 aF = *(const bf16x8*)(arow + kc * 32);
#pragma unroll
        for (int t = 0; t < 4; ++t) {
            bf16x8 bF = *(const bf16x8*)(WqkvT + (n0 + t * 16 + l16) * 256 + kc * 32 + quad * 8);
            acc[t] = __builtin_amdgcn_mfma_f32_16x16x32_bf16(aF, bF, acc[t], 0, 0, 0);
        }
    }
#pragma unroll
    for (int t = 0; t < 4; ++t) {
        const int cbase = n0 + t * 16;        // wave-uniform; never straddles a section/head
        const int sect = cbase >> 8;          // 0=q 1=k 2=v
        const int h = (cbase & 255) >> 5;
        const int d = (cbase & 31) + l16;
        const int m = m0 + wid * 16 + quad * 4;
        const int b = m >> 11;
        const int n = m & 2047;
        const int bh = b * 8 + h;
        if (sect == 0) {
            const float bw = rwb[h * 32 + d];
            const float br = rrb[h * 32 + d];
#pragma unroll
            for (int rr = 0; rr < 4; ++rr) {
                int idx = (bh * 2048 + n + rr) * 32 + d;
                q1w[idx] = f2b((acc[t][rr] + bw) * CS);
                q2w[idx] = f2b((acc[t][rr] + br) * CS);
            }
        } else if (sect == 1) {
#pragma unroll
            for (int rr = 0; rr < 4; ++rr)
                kw[(bh * 2048 + n + rr) * 32 + d] = f2b(acc[t][rr]);
        } else {
            ushort4 u;
            u.x = f2b(acc[t][0]); u.y = f2b(acc[t][1]);
            u.z = f2b(acc[t][2]); u.w = f2b(acc[t][3]);
            *(ushort4*)(vTw + (bh * 32 + d) * 2048 + n) = u;   // n is 4-aligned
        }
    }
}

// ---------------------------------------------------------------------------
// [Mx256] @ [256x256] bf16 GEMM, bf16 output (internal: r@Wr).
__global__ __launch_bounds__(256) void kgemm256b(
    const unsigned short* __restrict__ A, const unsigned short* __restrict__ BT,
    unsigned short* __restrict__ C)
{
    const int m0 = blockIdx.x * 64;
    const int n0 = blockIdx.y * 64;
    const int tid = threadIdx.x;
    const int wid = tid >> 6, lane = tid & 63;
    const int l16 = lane & 15, quad = lane >> 4;

    f32x4 acc[4] = {};
    const unsigned short* arow = A + (m0 + wid * 16 + l16) * 256 + quad * 8;
    for (int kc = 0; kc < 8; ++kc) {
        bf16x8 aF = *(const bf16x8*)(arow + kc * 32);
#pragma unroll
        for (int t = 0; t < 4; ++t) {
            bf16x8 bF = *(const bf16x8*)(BT + (n0 + t * 16 + l16) * 256 + kc * 32 + quad * 8);
            acc[t] = __builtin_amdgcn_mfma_f32_16x16x32_bf16(aF, bF, acc[t], 0, 0, 0);
        }
    }
#pragma unroll
    for (int t = 0; t < 4; ++t) {
        const int c = n0 + t * 16 + l16;
        const int m = m0 + wid * 16 + quad * 4;
#pragma unroll
        for (int rr = 0; rr < 4; ++rr)
            C[(m + rr) * 256 + c] = f2b(acc[t][rr]);
    }
}

// ---------------------------------------------------------------------------
// [Mx256] @ [256x256] bf16 GEMM, FLOAT32 output (final: ctx@Wout -> d_out).
__global__ __launch_bounds__(256) void kgemm256f(
    const unsigned short* __restrict__ A, const unsigned short* __restrict__ BT,
    float* __restrict__ C)
{
    const int m0 = blockIdx.x * 64;
    const int n0 = blockIdx.y * 64;
    const int tid = threadIdx.x;
    const int wid = tid >> 6, lane = tid & 63;
    const int l16 = lane & 15, quad = lane >> 4;

    f32x4 acc[4] = {};
    const unsigned short* arow = A + (m0 + wid * 16 + l16) * 256 + quad * 8;
    for (int kc = 0; kc < 8; ++kc) {
        bf16x8 aF = *(const bf16x8*)(arow + kc * 32);
#pragma unroll
        for (int t = 0; t < 4; ++t) {
            bf16x8 bF = *(const bf16x8*)(BT + (n0 + t * 16 + l16) * 256 + kc * 32 + quad * 8);
            acc[t] = __builtin_amdgcn_mfma_f32_16x16x32_bf16(aF, bF, acc[t], 0, 0, 0);
        }
    }
#pragma unroll
    for (int t = 0; t < 4; ++t) {
        const int c = n0 + t * 16 + l16;
        const int m = m0 + wid * 16 + quad * 4;
#pragma unroll
        for (int rr = 0; rr < 4; ++rr)
            C[(m + rr) * 256 + c] = acc[t][rr];
    }
}

// ---------------------------------------------------------------------------
// Fused attention, 8-wave blocks. Wave (iw, jh): iw = i-subtile (16 rows),
// jh = j-half (1024 cols, 16 tiles). Full occupancy: 1024 blocks x 8 waves =
// 8192 waves = machine capacity (4 blocks/CU, LDS 36.9KB/block).
// m=0 softmax (shift-invariant; |s*scale| <~ 2.5 -> no overflow).
// Fully-masked rows: p=1 forall j -> attn=1/2048 (halves: 1024+1024). OK.
// Pass A: scores -> p -> partial l, partial PV (p via double-buffered LDS,
//         one "memory" lgkmcnt barrier per tile for the cross-lane dep).
// Combine: partial l and PV across wave pairs (wid ^ 4) through LDS scratch
//         aliased onto pbuf (2x __syncthreads; pbuf dead after pass A).
// Pass B: recompute scores on own j-half, store attn = p/l as plain f32.
// Scores arrive pre-scaled by scale*log2e (folded into q1/q2) -> v_exp_f32.
__global__ __launch_bounds__(512, 8) void kattn(
    const unsigned short* __restrict__ q1w,  // [32][2048][32]
    const unsigned short* __restrict__ q2w,
    const unsigned short* __restrict__ kw,   // [32][2048][32]
    const unsigned short* __restrict__ vTw,  // [32][32][2048]
    const unsigned short* __restrict__ rr,   // flat [8][2048][32] (literal reshape of r@Wr)
    const int* __restrict__ mw,              // [4][2048] (i=0 true)
    float* __restrict__ attn,                // [32][2048][2048] f32
    unsigned short* __restrict__ ctx)        // [4][2048][256] bf16 (b, i, h*32+d)
{
    __shared__ __align__(16) unsigned short pbuf[8][2][16][72];  // 36,864 B

    // bh-clustered XCD swizzle (bijective: blk = (blk&7) + 8*idx)
    const int blk = blockIdx.x;              // 1024 = 32 bh * 32 i-tiles
    const int idx = blk >> 3;
    const int bh = ((blk & 7) << 2) | (idx >> 5);
    const int it = idx & 31;
    const int b = bh >> 3, h = bh & 7;
    const int tid = threadIdx.x;
    const int wid = tid >> 6, lane = tid & 63;
    const int iw = wid & 3, jh = wid >> 2;
    const int l16 = lane & 15, quad = lane >> 4;
    const int i0 = it * 64 + iw * 16;
    const int jt0 = jh * 16, jt1 = jt0 + 16;

    const bf16x8 a1 = *(const bf16x8*)(q1w + (bh * 2048 + i0 + l16) * 32 + quad * 8);
    const bf16x8 a2 = *(const bf16x8*)(q2w + (bh * 2048 + i0 + l16) * 32 + quad * 8);

    const int* mwb = mw + b * 2048;
    float mi[4];
#pragma unroll
    for (int r = 0; r < 4; ++r)
        mi[r] = mwb[i0 + quad * 4 + r] ? 1.f : 0.f;

    const unsigned short* kbase = kw + bh * 2048 * 32;
    const unsigned short* rbase = rr + h * 65536;
    const unsigned short* vbase = vTw + bh * 32 * 2048;

    float lsum[4] = {0.f, 0.f, 0.f, 0.f};
    f32x4 oacc[2] = {};
    unsigned short (*pbw)[16][72] = pbuf[wid];

    // ---- pass A: partial l + partial PV over own j-half ----
    for (int jt = jt0; jt < jt1; ++jt) {
        const int j0 = jt * 64;
        unsigned short (*pb)[72] = pbw[jt & 1];
        f32x4 s[4];
#pragma unroll
        for (int t = 0; t < 4; ++t) {
            bf16x8 bK = *(const bf16x8*)(kbase + (j0 + t * 16 + l16) * 32 + quad * 8);
            bf16x8 bR = *(const bf16x8*)(rbase + (j0 + t * 16 + l16) * 32 + quad * 8);
            f32x4 z = {};
            z = __builtin_amdgcn_mfma_f32_16x16x32_bf16(a1, bK, z, 0, 0, 0);
            s[t] = __builtin_amdgcn_mfma_f32_16x16x32_bf16(a2, bR, z, 0, 0, 0);
        }
#pragma unroll
        for (int t = 0; t < 4; ++t) {
            const float mj = mwb[j0 + t * 16 + l16] ? 1.f : 0.f;
#pragma unroll
            for (int r = 0; r < 4; ++r) {
                float p = (mi[r] == 0.f) ? 1.f : ((mj != 0.f) ? exp2_fast(s[t][r]) : 0.f);
                lsum[r] += p;
                pb[quad * 4 + r][t * 16 + l16] = f2b(p);
            }
        }
        // Cross-lane dep: lanes read rows other lanes wrote. One ordering
        // point per tile (double buffer covers the WAR side).
        asm volatile("s_waitcnt lgkmcnt(0)" ::: "memory");
#pragma unroll
        for (int kc = 0; kc < 2; ++kc) {
            bf16x8 pA = *(const bf16x8*)(&pb[l16][kc * 32 + quad * 8]);
#pragma unroll
            for (int dt = 0; dt < 2; ++dt) {
                bf16x8 bV = *(const bf16x8*)(vbase + (dt * 16 + l16) * 2048 + j0 + kc * 32 + quad * 8);
                oacc[dt] = __builtin_amdgcn_mfma_f32_16x16x32_bf16(pA, bV, oacc[dt], 0, 0, 0);
            }
        }
    }

    // ---- in-wave reduce: sum across the 16 lanes of each quad-group ----
    float vrow[4];
#pragma unroll
    for (int r = 0; r < 4; ++r) {
        float v = lsum[r];
        v += __shfl_xor(v, 1);
        v += __shfl_xor(v, 2);
        v += __shfl_xor(v, 4);
        v += __shfl_xor(v, 8);
        vrow[r] = v;   // row total for this j-half; identical across the 16-lane group
    }

    // ---- cross-wave combine (wid ^ 4): l and PV via LDS aliased on pbuf ----
    __syncthreads();                                   // pbuf dead from here
    float* lred = (float*)&pbuf[0][0][0][0];           // [8][16]
    float* ored = lred + 128;                          // [4][64][8]
    if (l16 == 0) {
#pragma unroll
        for (int r = 0; r < 4; ++r)
            lred[wid * 16 + quad * 4 + r] = vrow[r];
    }
    if (jh == 1) {
#pragma unroll
        for (int dt = 0; dt < 2; ++dt)
#pragma unroll
            for (int r = 0; r < 4; ++r)
                ored[(iw * 64 + lane) * 8 + dt * 4 + r] = oacc[dt][r];
    }
    __syncthreads();
    float invl[4];
#pragma unroll
    for (int r = 0; r < 4; ++r)
        invl[r] = 1.0f / (vrow[r] + lred[(wid ^ 4) * 16 + quad * 4 + r]);
    if (jh == 0) {
#pragma unroll
        for (int dt = 0; dt < 2; ++dt)
#pragma unroll
            for (int r = 0; r < 4; ++r)
                oacc[dt][r] += ored[(iw * 64 + lane) * 8 + dt * 4 + r];
    }

    // ---- pass B: recompute scores on own j-half, store normalized attn ----
    float* abase = attn + (bh * 2048 + i0) * 2048;
    for (int jt = jt0; jt < jt1; ++jt) {
        const int j0 = jt * 64;
        f32x4 s[4];
#pragma unroll
        for (int t = 0; t < 4; ++t) {
            bf16x8 bK = *(const bf16x8*)(kbase + (j0 + t * 16 + l16) * 32 + quad * 8);
            bf16x8 bR = *(const bf16x8*)(rbase + (j0 + t * 16 + l16) * 32 + quad * 8);
            f32x4 z = {};
            z = __builtin_amdgcn_mfma_f32_16x16x32_bf16(a1, bK, z, 0, 0, 0);
            s[t] = __builtin_amdgcn_mfma_f32_16x16x32_bf16(a2, bR, z, 0, 0, 0);
        }
#pragma unroll
        for (int t = 0; t < 4; ++t) {
            const float mj = mwb[j0 + t * 16 + l16] ? 1.f : 0.f;
            float* dst = abase + j0 + t * 16 + l16 + (quad * 4) * 2048;
#pragma unroll
            for (int r = 0; r < 4; ++r) {
                float p = (mi[r] == 0.f) ? 1.f : ((mj != 0.f) ? exp2_fast(s[t][r]) : 0.f);
                dst[r * 2048] = p * invl[r];
            }
        }
    }

    // ---- epilogue: O / l -> ctx (bf16 internal); combined halves live in jh==0 ----
    if (jh == 0) {
#pragma unroll
        for (int dt = 0; dt < 2; ++dt)
#pragma unroll
            for (int r = 0; r < 4; ++r) {
                float o = oacc[dt][r] * invl[r];
                ctx[(b * 2048 + i0 + quad * 4 + r) * 256 + h * 32 + dt * 16 + l16] = f2b(o);
            }
    }
}

// ---------------------------------------------------------------------------
extern "C" void kernel_launch(void* const* d_in, const int* in_sizes, int n_in,
                              void* d_out, int out_size, void* d_ws, size_t ws_size,
                              hipStream_t stream) {
    const float* w    = (const float*)d_in[0];  // [4][2048][256]
    const float* r    = (const float*)d_in[1];  // [2048][256]
    const int*   am   = (const int*)d_in[2];    // [4][2047]
    const float* Wqkv = (const float*)d_in[3];  // [256][768]
    const float* Wr   = (const float*)d_in[4];  // [256][256]
    const float* Wout = (const float*)d_in[5];  // [256][256]
    const float* rwb  = (const float*)d_in[6];  // [8][1][32]
    const float* rrb  = (const float*)d_in[7];  // [8][1][32]

    float* out  = (float*)d_out;                // [4][2048][256] f32
    float* attn = out + 4 * 2048 * 256;         // [4][8][2048][2048] f32

    unsigned short* ws    = (unsigned short*)d_ws;          // ~27 MB bf16 scratch
    unsigned short* wb    = ws;                             // 2,097,152
    unsigned short* rb    = wb + 2097152;                   // 524,288
    unsigned short* q1w   = rb + 524288;                    // 2,097,152
    unsigned short* q2w   = q1w + 2097152;
    unsigned short* kw    = q2w + 2097152;
    unsigned short* vTw   = kw + 2097152;
    unsigned short* rrw   = vTw + 2097152;                  // 524,288
    unsigned short* ctx   = rrw + 524288;                   // 2,097,152
    unsigned short* WqkvT = ctx + 2097152;                  // 196,608
    unsigned short* WrT   = WqkvT + 196608;                 // 65,536
    unsigned short* WoutT = WrT + 65536;                    // 65,536
    int*            mwp   = (int*)(WoutT + 65536);          // 8,192 ints

    kprep    <<<dim3(11558),   dim3(256), 0, stream>>>(w, r, Wqkv, Wr, Wout, am,
                                                       wb, rb, WqkvT, WrT, WoutT, mwp);
    kqkv     <<<dim3(128, 12), dim3(256), 0, stream>>>(wb, WqkvT, rwb, rrb, q1w, q2w, kw, vTw);
    kgemm256b<<<dim3(32, 4),   dim3(256), 0, stream>>>(rb, WrT, rrw);
    kattn    <<<dim3(1024),    dim3(512), 0, stream>>>(q1w, q2w, kw, vTw, rrw, mwp, attn, ctx);
    kgemm256f<<<dim3(128, 4),  dim3(256), 0, stream>>>(ctx, WoutT, out);
}

// Round 5
// 772.968 us; speedup vs baseline: 1.1119x; 1.1119x over previous
//
#include <hip/hip_runtime.h>

// RelativeLearnableAttention — MI355X (round 10)
// B=4 N=2048 DIM=256 H=8 D=32, scale = 1/16.
// Contract (established empirically R1–R6): inputs f32, mask int32,
// d_out = FLOAT32 (out [4,2048,256] ++ attn [4,8,2048,2048]).
// Internals: bf16 MFMA pipeline (kprep converts once); final stores f32.
// R10: REVERT R9 grid (859us; 512-thr/64-VGPR cap -> spills; occupancy theory
// falsified: 2x waves regressed). Attack the pass-B STORE PATTERN instead:
//  - old: wave-store = 4 rows x 64B segments at 8KB stride -> same-L2-channel
//    serialization, measured 1.8 TB/s (fill kernel: 6.2 TB/s on same path).
//  - new: p*invl transposed through per-wave f32 LDS tile; store float4,
//    quarter-wave per row -> 256B-contiguous segments, channel-spread.
//  - grid back to 1024 x 256thr (4 waves), no prefetch arrays (R8-neutral).

typedef short bf16x8 __attribute__((ext_vector_type(8)));
typedef float f32x4 __attribute__((ext_vector_type(4)));

static __device__ __forceinline__ unsigned short f2b(float f) {
    union { float f; unsigned int u; } x; x.f = f;
    unsigned int r = x.u + 0x7fffu + ((x.u >> 16) & 1u);   // RNE
    return (unsigned short)(r >> 16);
}

static __device__ __forceinline__ float exp2_fast(float x) {
    float r;
    asm("v_exp_f32 %0, %1" : "=v"(r) : "v"(x));   // D = 2^S0
    return r;
}

// ---------------------------------------------------------------------------
// Prep: f32->bf16 of w, r; transpose+convert Wqkv/Wr/Wout; mask -> mw[b][i]
// (left-pad True). 12 MB traffic.
__global__ __launch_bounds__(256) void kprep(
    const float* __restrict__ w, const float* __restrict__ r,
    const float* __restrict__ Wqkv, const float* __restrict__ Wr,
    const float* __restrict__ Wout, const int* __restrict__ amask,
    unsigned short* __restrict__ wb, unsigned short* __restrict__ rb,
    unsigned short* __restrict__ WqkvT, unsigned short* __restrict__ WrT,
    unsigned short* __restrict__ WoutT, int* __restrict__ mw)
{
    int o = blockIdx.x * 256 + threadIdx.x;
    if (o < 2097152) { wb[o] = f2b(w[o]); return; }
    o -= 2097152;
    if (o < 524288) { rb[o] = f2b(r[o]); return; }
    o -= 524288;
    if (o < 196608) { int n = o >> 8, k = o & 255; WqkvT[o] = f2b(Wqkv[k * 768 + n]); return; }
    o -= 196608;
    if (o < 65536) { int n = o >> 8, k = o & 255; WrT[o] = f2b(Wr[k * 256 + n]); return; }
    o -= 65536;
    if (o < 65536) { int n = o >> 8, k = o & 255; WoutT[o] = f2b(Wout[k * 256 + n]); return; }
    o -= 65536;
    {   // o in [0, 8192)
        const int b = o >> 11, i = o & 2047;
        mw[o] = (i == 0) ? 1 : (amask[b * 2047 + i - 1] != 0);
    }
}

// ---------------------------------------------------------------------------
// QKV GEMM: [8192x256] @ [256x768]; epilogue splits q/k/v, adds f32 biases to q,
// writes q1=(q+r_w_bias)*CS, q2=(q+r_r_bias)*CS (CS = scale*log2e folded so the
// attention kernel can use raw v_exp_f32), k as [bh][n][32], v transposed [bh][32][n].
__global__ __launch_bounds__(256) void kqkv(
    const unsigned short* __restrict__ w,      // [8192][256] bf16
    const unsigned short* __restrict__ WqkvT,  // [768][256] bf16
    const float* __restrict__ rwb,             // [256] f32 (h*32+d)
    const float* __restrict__ rrb,             // [256] f32
    unsigned short* __restrict__ q1w,          // [32][2048][32]
    unsigned short* __restrict__ q2w,
    unsigned short* __restrict__ kw,           // [32][2048][32]
    unsigned short* __restrict__ vTw)          // [32][32][2048]
{
    const int m0 = blockIdx.x * 64;
    const int n0 = blockIdx.y * 64;
    const int tid = threadIdx.x;
    const int wid = tid >> 6, lane = tid & 63;
    const int l16 = lane & 15, quad = lane >> 4;

    const float CS = 0.09016844f;   // (1/16) * log2(e)

    f32x4 acc[4] = {};
    const unsigned short* arow = w + (m0 + wid * 16 + l16) * 256 + quad * 8;
    for (int kc = 0; kc < 8; ++kc) {
        bf16x8 aF = *(const bf16x8*)(arow + kc * 32);
#pragma unroll
        for (int t = 0; t < 4; ++t) {
            bf16x8 bF = *(const bf16x8*)(WqkvT + (n0 + t * 16 + l16) * 256 + kc * 32 + quad * 8);
            acc[t] = __builtin_amdgcn_mfma_f32_16x16x32_bf16(aF, bF, acc[t], 0, 0, 0);
        }
    }
#pragma unroll
    for (int t = 0; t < 4; ++t) {
        const int cbase = n0 + t * 16;        // wave-uniform; never straddles a section/head
        const int sect = cbase >> 8;          // 0=q 1=k 2=v
        const int h = (cbase & 255) >> 5;
        const int d = (cbase & 31) + l16;
        const int m = m0 + wid * 16 + quad * 4;
        const int b = m >> 11;
        const int n = m & 2047;
        const int bh = b * 8 + h;
        if (sect == 0) {
            const float bw = rwb[h * 32 + d];
            const float br = rrb[h * 32 + d];
#pragma unroll
            for (int rr = 0; rr < 4; ++rr) {
                int idx = (bh * 2048 + n + rr) * 32 + d;
                q1w[idx] = f2b((acc[t][rr] + bw) * CS);
                q2w[idx] = f2b((acc[t][rr] + br) * CS);
            }
        } else if (sect == 1) {
#pragma unroll
            for (int rr = 0; rr < 4; ++rr)
                kw[(bh * 2048 + n + rr) * 32 + d] = f2b(acc[t][rr]);
        } else {
            ushort4 u;
            u.x = f2b(acc[t][0]); u.y = f2b(acc[t][1]);
            u.z = f2b(acc[t][2]); u.w = f2b(acc[t][3]);
            *(ushort4*)(vTw + (bh * 32 + d) * 2048 + n) = u;   // n is 4-aligned
        }
    }
}

// ---------------------------------------------------------------------------
// [Mx256] @ [256x256] bf16 GEMM, bf16 output (internal: r@Wr).
__global__ __launch_bounds__(256) void kgemm256b(
    const unsigned short* __restrict__ A, const unsigned short* __restrict__ BT,
    unsigned short* __restrict__ C)
{
    const int m0 = blockIdx.x * 64;
    const int n0 = blockIdx.y * 64;
    const int tid = threadIdx.x;
    const int wid = tid >> 6, lane = tid & 63;
    const int l16 = lane & 15, quad = lane >> 4;

    f32x4 acc[4] = {};
    const unsigned short* arow = A + (m0 + wid * 16 + l16) * 256 + quad * 8;
    for (int kc = 0; kc < 8; ++kc) {
        bf16x8 aF = *(const bf16x8*)(arow + kc * 32);
#pragma unroll
        for (int t = 0; t < 4; ++t) {
            bf16x8 bF = *(const bf16x8*)(BT + (n0 + t * 16 + l16) * 256 + kc * 32 + quad * 8);
            acc[t] = __builtin_amdgcn_mfma_f32_16x16x32_bf16(aF, bF, acc[t], 0, 0, 0);
        }
    }
#pragma unroll
    for (int t = 0; t < 4; ++t) {
        const int c = n0 + t * 16 + l16;
        const int m = m0 + wid * 16 + quad * 4;
#pragma unroll
        for (int rr = 0; rr < 4; ++rr)
            C[(m + rr) * 256 + c] = f2b(acc[t][rr]);
    }
}

// ---------------------------------------------------------------------------
// [Mx256] @ [256x256] bf16 GEMM, FLOAT32 output (final: ctx@Wout -> d_out).
__global__ __launch_bounds__(256) void kgemm256f(
    const unsigned short* __restrict__ A, const unsigned short* __restrict__ BT,
    float* __restrict__ C)
{
    const int m0 = blockIdx.x * 64;
    const int n0 = blockIdx.y * 64;
    const int tid = threadIdx.x;
    const int wid = tid >> 6, lane = tid & 63;
    const int l16 = lane & 15, quad = lane >> 4;

    f32x4 acc[4] = {};
    const unsigned short* arow = A + (m0 + wid * 16 + l16) * 256 + quad * 8;
    for (int kc = 0; kc < 8; ++kc) {
        bf16x8 aF = *(const bf16x8*)(arow + kc * 32);
#pragma unroll
        for (int t = 0; t < 4; ++t) {
            bf16x8 bF = *(const bf16x8*)(BT + (n0 + t * 16 + l16) * 256 + kc * 32 + quad * 8);
            acc[t] = __builtin_amdgcn_mfma_f32_16x16x32_bf16(aF, bF, acc[t], 0, 0, 0);
        }
    }
#pragma unroll
    for (int t = 0; t < 4; ++t) {
        const int c = n0 + t * 16 + l16;
        const int m = m0 + wid * 16 + quad * 4;
#pragma unroll
        for (int rr = 0; rr < 4; ++rr)
            C[(m + rr) * 256 + c] = acc[t][rr];
    }
}

// ---------------------------------------------------------------------------
// Fused attention. Block = 4 independent waves; wave owns 16 rows, sweeps all 2048 j.
// m=0 softmax (shift-invariant; |s*scale| <~ 2.5 -> no overflow).
// Fully-masked rows: p=1 forall j -> attn=1/2048 (matches reference).
// Pass A: scores -> p -> l += p, PV accumulate (p via double-buffered bf16 LDS;
//         one "memory" lgkmcnt barrier per tile orders the cross-lane dep).
// Pass B: recompute scores; p*invl goes through a per-wave f32 LDS tile and is
//         stored as float4, quarter-wave per row -> 256B-CONTIGUOUS segments
//         (old pattern: 4 rows x 64B @ 8KB stride -> L2-channel serialization,
//         capped at 1.8 TB/s; fill kernel does 6.2 TB/s with contiguous stores).
// Scores arrive pre-scaled by scale*log2e (folded into q1/q2) -> v_exp_f32.
__global__ __launch_bounds__(256, 4) void kattn(
    const unsigned short* __restrict__ q1w,  // [32][2048][32]
    const unsigned short* __restrict__ q2w,
    const unsigned short* __restrict__ kw,   // [32][2048][32]
    const unsigned short* __restrict__ vTw,  // [32][32][2048]
    const unsigned short* __restrict__ rr,   // flat [8][2048][32] (literal reshape of r@Wr)
    const int* __restrict__ mw,              // [4][2048] (i=0 true)
    float* __restrict__ attn,                // [32][2048][2048] f32
    unsigned short* __restrict__ ctx)        // [4][2048][256] bf16 (b, i, h*32+d)
{
    __shared__ __align__(16) unsigned short pbuf[4][2][16][72];  // pass A repack (18.4 KB)
    __shared__ __align__(16) float          fbuf[4][16][68];     // pass B f32 transpose (17.4 KB)

    // bh-clustered XCD swizzle (bijective: blk = (blk&7) + 8*idx)
    const int blk = blockIdx.x;              // 1024 = 32 bh * 32 i-tiles
    const int idx = blk >> 3;
    const int bh = ((blk & 7) << 2) | (idx >> 5);
    const int it = idx & 31;
    const int b = bh >> 3, h = bh & 7;
    const int tid = threadIdx.x;
    const int wid = tid >> 6, lane = tid & 63;
    const int l16 = lane & 15, quad = lane >> 4;
    const int i0 = it * 64 + wid * 16;

    const bf16x8 a1 = *(const bf16x8*)(q1w + (bh * 2048 + i0 + l16) * 32 + quad * 8);
    const bf16x8 a2 = *(const bf16x8*)(q2w + (bh * 2048 + i0 + l16) * 32 + quad * 8);

    const int* mwb = mw + b * 2048;
    float mi[4];
#pragma unroll
    for (int r = 0; r < 4; ++r)
        mi[r] = mwb[i0 + quad * 4 + r] ? 1.f : 0.f;

    const unsigned short* kbase = kw + bh * 2048 * 32;
    const unsigned short* rbase = rr + h * 65536;
    const unsigned short* vbase = vTw + bh * 32 * 2048;

    float lsum[4] = {0.f, 0.f, 0.f, 0.f};
    f32x4 oacc[2] = {};

    // ---- pass A: l accumulation + PV ----
    for (int jt = 0; jt < 32; ++jt) {
        const int j0 = jt * 64;
        unsigned short (*pb)[72] = pbuf[wid][jt & 1];
        f32x4 s[4];
#pragma unroll
        for (int t = 0; t < 4; ++t) {
            bf16x8 bK = *(const bf16x8*)(kbase + (j0 + t * 16 + l16) * 32 + quad * 8);
            bf16x8 bR = *(const bf16x8*)(rbase + (j0 + t * 16 + l16) * 32 + quad * 8);
            f32x4 z = {};
            z = __builtin_amdgcn_mfma_f32_16x16x32_bf16(a1, bK, z, 0, 0, 0);
            s[t] = __builtin_amdgcn_mfma_f32_16x16x32_bf16(a2, bR, z, 0, 0, 0);
        }
#pragma unroll
        for (int t = 0; t < 4; ++t) {
            const float mj = mwb[j0 + t * 16 + l16] ? 1.f : 0.f;
#pragma unroll
            for (int r = 0; r < 4; ++r) {
                float p = (mi[r] == 0.f) ? 1.f : ((mj != 0.f) ? exp2_fast(s[t][r]) : 0.f);
                lsum[r] += p;
                pb[quad * 4 + r][t * 16 + l16] = f2b(p);
            }
        }
        // Cross-lane dep: lanes read rows other lanes wrote. One ordering
        // point per tile (double buffer covers the WAR side).
        asm volatile("s_waitcnt lgkmcnt(0)" ::: "memory");
#pragma unroll
        for (int kc = 0; kc < 2; ++kc) {
            bf16x8 pA = *(const bf16x8*)(&pb[l16][kc * 32 + quad * 8]);
#pragma unroll
            for (int dt = 0; dt < 2; ++dt) {
                bf16x8 bV = *(const bf16x8*)(vbase + (dt * 16 + l16) * 2048 + j0 + kc * 32 + quad * 8);
                oacc[dt] = __builtin_amdgcn_mfma_f32_16x16x32_bf16(pA, bV, oacc[dt], 0, 0, 0);
            }
        }
    }

    // ---- finalize l: sum across the 16 lanes of each quad-group ----
    float invl[4];
#pragma unroll
    for (int r = 0; r < 4; ++r) {
        float v = lsum[r];
        v += __shfl_xor(v, 1);
        v += __shfl_xor(v, 2);
        v += __shfl_xor(v, 4);
        v += __shfl_xor(v, 8);
        invl[r] = 1.0f / v;
    }

    // ---- pass B: recompute scores; transpose via f32 LDS; contiguous stores ----
    float (*fb)[68] = fbuf[wid];
    float* abase = attn + (bh * 2048 + i0) * 2048;
    for (int jt = 0; jt < 32; ++jt) {
        const int j0 = jt * 64;
        f32x4 s[4];
#pragma unroll
        for (int t = 0; t < 4; ++t) {
            bf16x8 bK = *(const bf16x8*)(kbase + (j0 + t * 16 + l16) * 32 + quad * 8);
            bf16x8 bR = *(const bf16x8*)(rbase + (j0 + t * 16 + l16) * 32 + quad * 8);
            f32x4 z = {};
            z = __builtin_amdgcn_mfma_f32_16x16x32_bf16(a1, bK, z, 0, 0, 0);
            s[t] = __builtin_amdgcn_mfma_f32_16x16x32_bf16(a2, bR, z, 0, 0, 0);
        }
#pragma unroll
        for (int t = 0; t < 4; ++t) {
            const float mj = mwb[j0 + t * 16 + l16] ? 1.f : 0.f;
#pragma unroll
            for (int r = 0; r < 4; ++r) {
                float p = (mi[r] == 0.f) ? 1.f : ((mj != 0.f) ? exp2_fast(s[t][r]) : 0.f);
                fb[quad * 4 + r][t * 16 + l16] = p * invl[r];
            }
        }
        asm volatile("s_waitcnt lgkmcnt(0)" ::: "memory");   // cross-lane write->read
#pragma unroll
        for (int c = 0; c < 4; ++c) {
            // quarter-wave per row: lanes l16=0..15 cover one row's 64 floats
            // as float4s -> 256B-contiguous segments (4 rows per instruction).
            const int rw = c * 4 + quad;
            f32x4 v = *(const f32x4*)&fb[rw][l16 * 4];
            *(f32x4*)(abase + (rw)*2048 + j0 + l16 * 4) = v;
        }
        asm volatile("s_waitcnt lgkmcnt(0)" ::: "memory");   // WAR before next overwrite
    }

    // ---- epilogue: O / l -> ctx (bf16 internal) ----
#pragma unroll
    for (int dt = 0; dt < 2; ++dt)
#pragma unroll
        for (int r = 0; r < 4; ++r) {
            float o = oacc[dt][r] * invl[r];
            ctx[(b * 2048 + i0 + quad * 4 + r) * 256 + h * 32 + dt * 16 + l16] = f2b(o);
        }
}

// ---------------------------------------------------------------------------
extern "C" void kernel_launch(void* const* d_in, const int* in_sizes, int n_in,
                              void* d_out, int out_size, void* d_ws, size_t ws_size,
                              hipStream_t stream) {
    const float* w    = (const float*)d_in[0];  // [4][2048][256]
    const float* r    = (const float*)d_in[1];  // [2048][256]
    const int*   am   = (const int*)d_in[2];    // [4][2047]
    const float* Wqkv = (const float*)d_in[3];  // [256][768]
    const float* Wr   = (const float*)d_in[4];  // [256][256]
    const float* Wout = (const float*)d_in[5];  // [256][256]
    const float* rwb  = (const float*)d_in[6];  // [8][1][32]
    const float* rrb  = (const float*)d_in[7];  // [8][1][32]

    float* out  = (float*)d_out;                // [4][2048][256] f32
    float* attn = out + 4 * 2048 * 256;         // [4][8][2048][2048] f32

    unsigned short* ws    = (unsigned short*)d_ws;          // ~27 MB bf16 scratch
    unsigned short* wb    = ws;                             // 2,097,152
    unsigned short* rb    = wb + 2097152;                   // 524,288
    unsigned short* q1w   = rb + 524288;                    // 2,097,152
    unsigned short* q2w   = q1w + 2097152;
    unsigned short* kw    = q2w + 2097152;
    unsigned short* vTw   = kw + 2097152;
    unsigned short* rrw   = vTw + 2097152;                  // 524,288
    unsigned short* ctx   = rrw + 524288;                   // 2,097,152
    unsigned short* WqkvT = ctx + 2097152;                  // 196,608
    unsigned short* WrT   = WqkvT + 196608;                 // 65,536
    unsigned short* WoutT = WrT + 65536;                    // 65,536
    int*            mwp   = (int*)(WoutT + 65536);          // 8,192 ints

    kprep    <<<dim3(11558),   dim3(256), 0, stream>>>(w, r, Wqkv, Wr, Wout, am,
                                                       wb, rb, WqkvT, WrT, WoutT, mwp);
    kqkv     <<<dim3(128, 12), dim3(256), 0, stream>>>(wb, WqkvT, rwb, rrb, q1w, q2w, kw, vTw);
    kgemm256b<<<dim3(32, 4),   dim3(256), 0, stream>>>(rb, WrT, rrw);
    kattn    <<<dim3(1024),    dim3(256), 0, stream>>>(q1w, q2w, kw, vTw, rrw, mwp, attn, ctx);
    kgemm256f<<<dim3(128, 4),  dim3(256), 0, stream>>>(ctx, WoutT, out);
}

// Round 6
// 755.052 us; speedup vs baseline: 1.1382x; 1.0237x over previous
//
#include <hip/hip_runtime.h>

// RelativeLearnableAttention — MI355X (round 11)
// B=4 N=2048 DIM=256 H=8 D=32, scale = 1/16.
// Contract: inputs f32, mask int32, d_out = f32 (out [4,2048,256] ++ attn [4,8,2048,2048]).
// R11: SPLIT kattn. Five rounds of in-place micro-levers were neutral (766-773)
// or negative; counters say latency-bound (MfmaUtil 5%, VALU 17%, Occ 44%,
// 13K cy/tile vs ~800 cy of chain work). Structural fix:
//  - kattn1: l + PV + ctx only. Mask staged to LDS as f32, folded as multiply
//    (p = exp2(s)*mjf) -> no global mask loads in the chain. Writes invl (256KB).
//  - kattn2: pure streaming attn writer. Recompute scores, scale by invl, store.
//    NO LDS dep, NO barriers, lean body -> grid 2048 x 4 waves = 8192 waves =
//    100% occupancy via __launch_bounds__(256,8) (old fat kernel fit 56 VGPR).

typedef short bf16x8 __attribute__((ext_vector_type(8)));
typedef float f32x4 __attribute__((ext_vector_type(4)));

static __device__ __forceinline__ unsigned short f2b(float f) {
    union { float f; unsigned int u; } x; x.f = f;
    unsigned int r = x.u + 0x7fffu + ((x.u >> 16) & 1u);   // RNE
    return (unsigned short)(r >> 16);
}

static __device__ __forceinline__ float exp2_fast(float x) {
    float r;
    asm("v_exp_f32 %0, %1" : "=v"(r) : "v"(x));   // D = 2^S0
    return r;
}

// ---------------------------------------------------------------------------
// Prep: f32->bf16 of w, r; transpose+convert Wqkv/Wr/Wout; mask -> mwf[b][i]
// as FLOAT 0/1 (left-pad True). ~12 MB traffic.
__global__ __launch_bounds__(256) void kprep(
    const float* __restrict__ w, const float* __restrict__ r,
    const float* __restrict__ Wqkv, const float* __restrict__ Wr,
    const float* __restrict__ Wout, const int* __restrict__ amask,
    unsigned short* __restrict__ wb, unsigned short* __restrict__ rb,
    unsigned short* __restrict__ WqkvT, unsigned short* __restrict__ WrT,
    unsigned short* __restrict__ WoutT, float* __restrict__ mwf)
{
    int o = blockIdx.x * 256 + threadIdx.x;
    if (o < 2097152) { wb[o] = f2b(w[o]); return; }
    o -= 2097152;
    if (o < 524288) { rb[o] = f2b(r[o]); return; }
    o -= 524288;
    if (o < 196608) { int n = o >> 8, k = o & 255; WqkvT[o] = f2b(Wqkv[k * 768 + n]); return; }
    o -= 196608;
    if (o < 65536) { int n = o >> 8, k = o & 255; WrT[o] = f2b(Wr[k * 256 + n]); return; }
    o -= 65536;
    if (o < 65536) { int n = o >> 8, k = o & 255; WoutT[o] = f2b(Wout[k * 256 + n]); return; }
    o -= 65536;
    if (o < 8192) {
        const int b = o >> 11, i = o & 2047;
        mwf[o] = (i == 0 || amask[b * 2047 + i - 1] != 0) ? 1.0f : 0.0f;
    }
}

// ---------------------------------------------------------------------------
// QKV GEMM: [8192x256] @ [256x768]; epilogue splits q/k/v, adds f32 biases to q,
// writes q1=(q+r_w_bias)*CS, q2=(q+r_r_bias)*CS (CS = scale*log2e folded so the
// attention kernels use raw v_exp_f32), k as [bh][n][32], v transposed [bh][32][n].
__global__ __launch_bounds__(256) void kqkv(
    const unsigned short* __restrict__ w,      // [8192][256] bf16
    const unsigned short* __restrict__ WqkvT,  // [768][256] bf16
    const float* __restrict__ rwb,             // [256] f32 (h*32+d)
    const float* __restrict__ rrb,             // [256] f32
    unsigned short* __restrict__ q1w,          // [32][2048][32]
    unsigned short* __restrict__ q2w,
    unsigned short* __restrict__ kw,           // [32][2048][32]
    unsigned short* __restrict__ vTw)          // [32][32][2048]
{
    const int m0 = blockIdx.x * 64;
    const int n0 = blockIdx.y * 64;
    const int tid = threadIdx.x;
    const int wid = tid >> 6, lane = tid & 63;
    const int l16 = lane & 15, quad = lane >> 4;

    const float CS = 0.09016844f;   // (1/16) * log2(e)

    f32x4 acc[4] = {};
    const unsigned short* arow = w + (m0 + wid * 16 + l16) * 256 + quad * 8;
    for (int kc = 0; kc < 8; ++kc) {
        bf16x8 aF = *(const bf16x8*)(arow + kc * 32);
#pragma unroll
        for (int t = 0; t < 4; ++t) {
            bf16x8 bF = *(const bf16x8*)(WqkvT + (n0 + t * 16 + l16) * 256 + kc * 32 + quad * 8);
            acc[t] = __builtin_amdgcn_mfma_f32_16x16x32_bf16(aF, bF, acc[t], 0, 0, 0);
        }
    }
#pragma unroll
    for (int t = 0; t < 4; ++t) {
        const int cbase = n0 + t * 16;        // wave-uniform; never straddles a section/head
        const int sect = cbase >> 8;          // 0=q 1=k 2=v
        const int h = (cbase & 255) >> 5;
        const int d = (cbase & 31) + l16;
        const int m = m0 + wid * 16 + quad * 4;
        const int b = m >> 11;
        const int n = m & 2047;
        const int bh = b * 8 + h;
        if (sect == 0) {
            const float bw = rwb[h * 32 + d];
            const float br = rrb[h * 32 + d];
#pragma unroll
            for (int rr = 0; rr < 4; ++rr) {
                int idx = (bh * 2048 + n + rr) * 32 + d;
                q1w[idx] = f2b((acc[t][rr] + bw) * CS);
                q2w[idx] = f2b((acc[t][rr] + br) * CS);
            }
        } else if (sect == 1) {
#pragma unroll
            for (int rr = 0; rr < 4; ++rr)
                kw[(bh * 2048 + n + rr) * 32 + d] = f2b(acc[t][rr]);
        } else {
            ushort4 u;
            u.x = f2b(acc[t][0]); u.y = f2b(acc[t][1]);
            u.z = f2b(acc[t][2]); u.w = f2b(acc[t][3]);
            *(ushort4*)(vTw + (bh * 32 + d) * 2048 + n) = u;   // n is 4-aligned
        }
    }
}

// ---------------------------------------------------------------------------
// [Mx256] @ [256x256] bf16 GEMM, bf16 output (internal: r@Wr).
__global__ __launch_bounds__(256) void kgemm256b(
    const unsigned short* __restrict__ A, const unsigned short* __restrict__ BT,
    unsigned short* __restrict__ C)
{
    const int m0 = blockIdx.x * 64;
    const int n0 = blockIdx.y * 64;
    const int tid = threadIdx.x;
    const int wid = tid >> 6, lane = tid & 63;
    const int l16 = lane & 15, quad = lane >> 4;

    f32x4 acc[4] = {};
    const unsigned short* arow = A + (m0 + wid * 16 + l16) * 256 + quad * 8;
    for (int kc = 0; kc < 8; ++kc) {
        bf16x8 aF = *(const bf16x8*)(arow + kc * 32);
#pragma unroll
        for (int t = 0; t < 4; ++t) {
            bf16x8 bF = *(const bf16x8*)(BT + (n0 + t * 16 + l16) * 256 + kc * 32 + quad * 8);
            acc[t] = __builtin_amdgcn_mfma_f32_16x16x32_bf16(aF, bF, acc[t], 0, 0, 0);
        }
    }
#pragma unroll
    for (int t = 0; t < 4; ++t) {
        const int c = n0 + t * 16 + l16;
        const int m = m0 + wid * 16 + quad * 4;
#pragma unroll
        for (int rr = 0; rr < 4; ++rr)
            C[(m + rr) * 256 + c] = f2b(acc[t][rr]);
    }
}

// ---------------------------------------------------------------------------
// [Mx256] @ [256x256] bf16 GEMM, FLOAT32 output (final: ctx@Wout -> d_out).
__global__ __launch_bounds__(256) void kgemm256f(
    const unsigned short* __restrict__ A, const unsigned short* __restrict__ BT,
    float* __restrict__ C)
{
    const int m0 = blockIdx.x * 64;
    const int n0 = blockIdx.y * 64;
    const int tid = threadIdx.x;
    const int wid = tid >> 6, lane = tid & 63;
    const int l16 = lane & 15, quad = lane >> 4;

    f32x4 acc[4] = {};
    const unsigned short* arow = A + (m0 + wid * 16 + l16) * 256 + quad * 8;
    for (int kc = 0; kc < 8; ++kc) {
        bf16x8 aF = *(const bf16x8*)(arow + kc * 32);
#pragma unroll
        for (int t = 0; t < 4; ++t) {
            bf16x8 bF = *(const bf16x8*)(BT + (n0 + t * 16 + l16) * 256 + kc * 32 + quad * 8);
            acc[t] = __builtin_amdgcn_mfma_f32_16x16x32_bf16(aF, bF, acc[t], 0, 0, 0);
        }
    }
#pragma unroll
    for (int t = 0; t < 4; ++t) {
        const int c = n0 + t * 16 + l16;
        const int m = m0 + wid * 16 + quad * 4;
#pragma unroll
        for (int rr = 0; rr < 4; ++rr)
            C[(m + rr) * 256 + c] = acc[t][rr];
    }
}

// ---------------------------------------------------------------------------
// kattn1: softmax denominators + PV context. NO attn stores.
// Block = 4 indep waves; wave owns 16 rows, sweeps all 2048 j.
// Mask staged once to LDS as f32; p = exp2(s)*mjf (multiply, no global loads
// in the chain). Fully-masked rows: p=1 forall j -> l=2048.
// Writes invl[bh][2048] f32 to workspace; ctx bf16.
__global__ __launch_bounds__(256, 4) void kattn1(
    const unsigned short* __restrict__ q1w,  // [32][2048][32]
    const unsigned short* __restrict__ q2w,
    const unsigned short* __restrict__ kw,   // [32][2048][32]
    const unsigned short* __restrict__ vTw,  // [32][32][2048]
    const unsigned short* __restrict__ rr,   // flat [8][2048][32]
    const float* __restrict__ mwf,           // [4][2048] f32 0/1
    float* __restrict__ invl_ws,             // [32][2048] f32
    unsigned short* __restrict__ ctx)        // [4][2048][256] bf16
{
    __shared__ __align__(16) unsigned short pbuf[4][2][16][72];  // 18.4 KB
    __shared__ __align__(16) float msk[2048];                    // 8 KB

    // bh-clustered XCD swizzle (bijective: blk = (blk&7) + 8*idx)
    const int blk = blockIdx.x;              // 1024 = 32 bh * 32 i-tiles
    const int idx = blk >> 3;
    const int bh = ((blk & 7) << 2) | (idx >> 5);
    const int it = idx & 31;
    const int b = bh >> 3, h = bh & 7;
    const int tid = threadIdx.x;
    const int wid = tid >> 6, lane = tid & 63;
    const int l16 = lane & 15, quad = lane >> 4;
    const int i0 = it * 64 + wid * 16;

    // stage mask row for this batch (2048 f32): 256 threads x 8
    {
        const float* src = mwf + b * 2048 + tid * 8;
        *(f32x4*)&msk[tid * 8]     = *(const f32x4*)(src);
        *(f32x4*)&msk[tid * 8 + 4] = *(const f32x4*)(src + 4);
    }
    __syncthreads();

    const bf16x8 a1 = *(const bf16x8*)(q1w + (bh * 2048 + i0 + l16) * 32 + quad * 8);
    const bf16x8 a2 = *(const bf16x8*)(q2w + (bh * 2048 + i0 + l16) * 32 + quad * 8);

    float mi[4];
#pragma unroll
    for (int r = 0; r < 4; ++r)
        mi[r] = msk[i0 + quad * 4 + r];

    const unsigned short* kbase = kw + bh * 2048 * 32;
    const unsigned short* rbase = rr + h * 65536;
    const unsigned short* vbase = vTw + bh * 32 * 2048;

    float lsum[4] = {0.f, 0.f, 0.f, 0.f};
    f32x4 oacc[2] = {};

    for (int jt = 0; jt < 32; ++jt) {
        const int j0 = jt * 64;
        unsigned short (*pb)[72] = pbuf[wid][jt & 1];
        f32x4 s[4];
#pragma unroll
        for (int t = 0; t < 4; ++t) {
            bf16x8 bK = *(const bf16x8*)(kbase + (j0 + t * 16 + l16) * 32 + quad * 8);
            bf16x8 bR = *(const bf16x8*)(rbase + (j0 + t * 16 + l16) * 32 + quad * 8);
            f32x4 z = {};
            z = __builtin_amdgcn_mfma_f32_16x16x32_bf16(a1, bK, z, 0, 0, 0);
            s[t] = __builtin_amdgcn_mfma_f32_16x16x32_bf16(a2, bR, z, 0, 0, 0);
        }
#pragma unroll
        for (int t = 0; t < 4; ++t) {
            const float mj = msk[j0 + t * 16 + l16];
#pragma unroll
            for (int r = 0; r < 4; ++r) {
                float p = (mi[r] == 0.f) ? 1.f : exp2_fast(s[t][r]) * mj;
                lsum[r] += p;
                pb[quad * 4 + r][t * 16 + l16] = f2b(p);
            }
        }
        // Cross-lane dep: lanes read rows other lanes wrote. One ordering
        // point per tile (double buffer covers the WAR side).
        asm volatile("s_waitcnt lgkmcnt(0)" ::: "memory");
#pragma unroll
        for (int kc = 0; kc < 2; ++kc) {
            bf16x8 pA = *(const bf16x8*)(&pb[l16][kc * 32 + quad * 8]);
#pragma unroll
            for (int dt = 0; dt < 2; ++dt) {
                bf16x8 bV = *(const bf16x8*)(vbase + (dt * 16 + l16) * 2048 + j0 + kc * 32 + quad * 8);
                oacc[dt] = __builtin_amdgcn_mfma_f32_16x16x32_bf16(pA, bV, oacc[dt], 0, 0, 0);
            }
        }
    }

    // finalize l: sum across the 16 lanes of each quad-group
    float invl[4];
#pragma unroll
    for (int r = 0; r < 4; ++r) {
        float v = lsum[r];
        v += __shfl_xor(v, 1);
        v += __shfl_xor(v, 2);
        v += __shfl_xor(v, 4);
        v += __shfl_xor(v, 8);
        invl[r] = 1.0f / v;
    }

    // write invl for kattn2
    if (l16 == 0) {
#pragma unroll
        for (int r = 0; r < 4; ++r)
            invl_ws[bh * 2048 + i0 + quad * 4 + r] = invl[r];
    }

    // epilogue: O / l -> ctx (bf16 internal)
#pragma unroll
    for (int dt = 0; dt < 2; ++dt)
#pragma unroll
        for (int r = 0; r < 4; ++r) {
            float o = oacc[dt][r] * invl[r];
            ctx[(b * 2048 + i0 + quad * 4 + r) * 256 + h * 32 + dt * 16 + l16] = f2b(o);
        }
}

// ---------------------------------------------------------------------------
// kattn2: pure streaming attn writer. Recompute scores, scale by invl, store.
// Grid 2048 blocks = (bh, i-tile 64, j-half 1024); 4 waves x 16 rows x 16 jt.
// No LDS cross-lane dep, no barriers -> compiler pipelines freely.
// 8192 waves = 100% occupancy (launch_bounds(256,8); lean body << 64 VGPR).
__global__ __launch_bounds__(256, 8) void kattn2(
    const unsigned short* __restrict__ q1w,  // [32][2048][32]
    const unsigned short* __restrict__ q2w,
    const unsigned short* __restrict__ kw,   // [32][2048][32]
    const unsigned short* __restrict__ rr,   // flat [8][2048][32]
    const float* __restrict__ mwf,           // [4][2048] f32 0/1
    const float* __restrict__ invl_ws,       // [32][2048] f32
    float* __restrict__ attn)                // [32][2048][2048] f32
{
    __shared__ __align__(16) float msk[1024];   // 4 KB (j-half mask)

    // bh-clustered XCD swizzle: XCD x owns bh 4x..4x+3 (256 blocks each)
    const int blk = blockIdx.x;              // 2048 = 32 bh * 32 it * 2 jh
    const int idx = blk >> 3;                // [0,256)
    const int bh = ((blk & 7) << 2) | (idx >> 6);
    const int rem = idx & 63;
    const int it = rem >> 1, jh = rem & 1;
    const int b = bh >> 3, h = bh & 7;
    const int tid = threadIdx.x;
    const int wid = tid >> 6, lane = tid & 63;
    const int l16 = lane & 15, quad = lane >> 4;
    const int i0 = it * 64 + wid * 16;
    const int jbase = jh * 1024;

    // stage j-half mask: 256 threads x 4
    *(f32x4*)&msk[tid * 4] = *(const f32x4*)(mwf + b * 2048 + jbase + tid * 4);
    __syncthreads();

    const bf16x8 a1 = *(const bf16x8*)(q1w + (bh * 2048 + i0 + l16) * 32 + quad * 8);
    const bf16x8 a2 = *(const bf16x8*)(q2w + (bh * 2048 + i0 + l16) * 32 + quad * 8);

    float scl[4], add[4];
#pragma unroll
    for (int r = 0; r < 4; ++r) {
        const int row = i0 + quad * 4 + r;
        const float iv = invl_ws[bh * 2048 + row];
        const float mi = mwf[b * 2048 + row];
        scl[r] = (mi == 0.f) ? 0.f : iv;   // v = exp2(s)*mj*scl + add
        add[r] = (mi == 0.f) ? iv  : 0.f;  // masked row -> uniform invl (=1/2048)
    }

    const unsigned short* kbase = kw + bh * 2048 * 32;
    const unsigned short* rbase = rr + h * 65536;
    float* abase = attn + (bh * 2048 + i0) * 2048;

    for (int jt = 0; jt < 16; ++jt) {
        const int jl = jt * 64;              // offset within j-half
        const int j0 = jbase + jl;           // global j
        f32x4 s[4];
#pragma unroll
        for (int t = 0; t < 4; ++t) {
            bf16x8 bK = *(const bf16x8*)(kbase + (j0 + t * 16 + l16) * 32 + quad * 8);
            bf16x8 bR = *(const bf16x8*)(rbase + (j0 + t * 16 + l16) * 32 + quad * 8);
            f32x4 z = {};
            z = __builtin_amdgcn_mfma_f32_16x16x32_bf16(a1, bK, z, 0, 0, 0);
            s[t] = __builtin_amdgcn_mfma_f32_16x16x32_bf16(a2, bR, z, 0, 0, 0);
        }
#pragma unroll
        for (int t = 0; t < 4; ++t) {
            const float mj = msk[jl + t * 16 + l16];
            float* dst = abase + j0 + t * 16 + l16 + (quad * 4) * 2048;
#pragma unroll
            for (int r = 0; r < 4; ++r) {
                float v = exp2_fast(s[t][r]) * mj * scl[r] + add[r];
                dst[r * 2048] = v;
            }
        }
    }
}

// ---------------------------------------------------------------------------
extern "C" void kernel_launch(void* const* d_in, const int* in_sizes, int n_in,
                              void* d_out, int out_size, void* d_ws, size_t ws_size,
                              hipStream_t stream) {
    const float* w    = (const float*)d_in[0];  // [4][2048][256]
    const float* r    = (const float*)d_in[1];  // [2048][256]
    const int*   am   = (const int*)d_in[2];    // [4][2047]
    const float* Wqkv = (const float*)d_in[3];  // [256][768]
    const float* Wr   = (const float*)d_in[4];  // [256][256]
    const float* Wout = (const float*)d_in[5];  // [256][256]
    const float* rwb  = (const float*)d_in[6];  // [8][1][32]
    const float* rrb  = (const float*)d_in[7];  // [8][1][32]

    float* out  = (float*)d_out;                // [4][2048][256] f32
    float* attn = out + 4 * 2048 * 256;         // [4][8][2048][2048] f32

    unsigned short* ws    = (unsigned short*)d_ws;          // ~27 MB scratch
    unsigned short* wb    = ws;                             // 2,097,152
    unsigned short* rb    = wb + 2097152;                   // 524,288
    unsigned short* q1w   = rb + 524288;                    // 2,097,152
    unsigned short* q2w   = q1w + 2097152;
    unsigned short* kw    = q2w + 2097152;
    unsigned short* vTw   = kw + 2097152;
    unsigned short* rrw   = vTw + 2097152;                  // 524,288
    unsigned short* ctx   = rrw + 524288;                   // 2,097,152
    unsigned short* WqkvT = ctx + 2097152;                  // 196,608
    unsigned short* WrT   = WqkvT + 196608;                 // 65,536
    unsigned short* WoutT = WrT + 65536;                    // 65,536
    float*          mwfp  = (float*)(WoutT + 65536);        // 8,192 f32 (32 KB)
    float*          invlp = mwfp + 8192;                    // 65,536 f32 (256 KB)

    kprep    <<<dim3(11552),   dim3(256), 0, stream>>>(w, r, Wqkv, Wr, Wout, am,
                                                       wb, rb, WqkvT, WrT, WoutT, mwfp);
    kqkv     <<<dim3(128, 12), dim3(256), 0, stream>>>(wb, WqkvT, rwb, rrb, q1w, q2w, kw, vTw);
    kgemm256b<<<dim3(32, 4),   dim3(256), 0, stream>>>(rb, WrT, rrw);
    kattn1   <<<dim3(1024),    dim3(256), 0, stream>>>(q1w, q2w, kw, vTw, rrw, mwfp, invlp, ctx);
    kattn2   <<<dim3(2048),    dim3(256), 0, stream>>>(q1w, q2w, kw, rrw, mwfp, invlp, attn);
    kgemm256f<<<dim3(128, 4),  dim3(256), 0, stream>>>(ctx, WoutT, out);
}

// Round 11
// 752.672 us; speedup vs baseline: 1.1418x; 1.0032x over previous
//
#include <hip/hip_runtime.h>

// RelativeLearnableAttention — MI355X (round 16)
// B=4 N=2048 DIM=256 H=8 D=32, scale = 1/16.
// Contract: inputs f32, mask int32, d_out = f32 (out [4,2048,256] ++ attn [4,8,2048,2048]).
// R16: FULL REVERT of kattn1 to the R11-validated LDS version (755us, absmax
// 4.88e-4). The 32x32 in-register rewrite (R12-R15) failed 4 rounds straight
// (0.88 / 1.26 / 0.87 / 7.08e-3); R15's covariance-magnitude residual says a
// subtle operand-mapping flaw survives my washout analysis — not resolvable by
// bench bisection. Banking the known-good state.
// Pipeline (all validated): kprep (f32 mask), kqkv (CS=scale*log2e folded into
// q1/q2), kgemm256b (r@Wr), kattn1 (l+PV+ctx, LDS p round-trip, 1 barrier/tile),
// kattn2 (pure streaming attn writer, 100% occupancy), kgemm256f (ctx@Wout).

typedef short bf16x8 __attribute__((ext_vector_type(8)));
typedef float f32x4  __attribute__((ext_vector_type(4)));

static __device__ __forceinline__ unsigned short f2b(float f) {
    union { float f; unsigned int u; } x; x.f = f;
    unsigned int r = x.u + 0x7fffu + ((x.u >> 16) & 1u);   // RNE
    return (unsigned short)(r >> 16);
}

static __device__ __forceinline__ float exp2_fast(float x) {
    float r;
    asm("v_exp_f32 %0, %1" : "=v"(r) : "v"(x));   // D = 2^S0
    return r;
}

// ---------------------------------------------------------------------------
// Prep: f32->bf16 of w, r; transpose+convert Wqkv/Wr/Wout; mask -> mwf[b][i]
// as FLOAT 0/1 (left-pad True). ~12 MB traffic.
__global__ __launch_bounds__(256) void kprep(
    const float* __restrict__ w, const float* __restrict__ r,
    const float* __restrict__ Wqkv, const float* __restrict__ Wr,
    const float* __restrict__ Wout, const int* __restrict__ amask,
    unsigned short* __restrict__ wb, unsigned short* __restrict__ rb,
    unsigned short* __restrict__ WqkvT, unsigned short* __restrict__ WrT,
    unsigned short* __restrict__ WoutT, float* __restrict__ mwf)
{
    int o = blockIdx.x * 256 + threadIdx.x;
    if (o < 2097152) { wb[o] = f2b(w[o]); return; }
    o -= 2097152;
    if (o < 524288) { rb[o] = f2b(r[o]); return; }
    o -= 524288;
    if (o < 196608) { int n = o >> 8, k = o & 255; WqkvT[o] = f2b(Wqkv[k * 768 + n]); return; }
    o -= 196608;
    if (o < 65536) { int n = o >> 8, k = o & 255; WrT[o] = f2b(Wr[k * 256 + n]); return; }
    o -= 65536;
    if (o < 65536) { int n = o >> 8, k = o & 255; WoutT[o] = f2b(Wout[k * 256 + n]); return; }
    o -= 65536;
    if (o < 8192) {
        const int b = o >> 11, i = o & 2047;
        mwf[o] = (i == 0 || amask[b * 2047 + i - 1] != 0) ? 1.0f : 0.0f;
    }
}

// ---------------------------------------------------------------------------
// QKV GEMM: [8192x256] @ [256x768]; epilogue splits q/k/v, adds f32 biases to q,
// writes q1=(q+r_w_bias)*CS, q2=(q+r_r_bias)*CS (CS = scale*log2e folded so the
// attention kernels use raw v_exp_f32), k as [bh][n][32], v transposed [bh][32][n].
__global__ __launch_bounds__(256) void kqkv(
    const unsigned short* __restrict__ w,      // [8192][256] bf16
    const unsigned short* __restrict__ WqkvT,  // [768][256] bf16
    const float* __restrict__ rwb,             // [256] f32 (h*32+d)
    const float* __restrict__ rrb,             // [256] f32
    unsigned short* __restrict__ q1w,          // [32][2048][32]
    unsigned short* __restrict__ q2w,
    unsigned short* __restrict__ kw,           // [32][2048][32]
    unsigned short* __restrict__ vTw)          // [32][32][2048]
{
    const int m0 = blockIdx.x * 64;
    const int n0 = blockIdx.y * 64;
    const int tid = threadIdx.x;
    const int wid = tid >> 6, lane = tid & 63;
    const int l16 = lane & 15, quad = lane >> 4;

    const float CS = 0.09016844f;   // (1/16) * log2(e)

    f32x4 acc[4] = {};
    const unsigned short* arow = w + (m0 + wid * 16 + l16) * 256 + quad * 8;
    for (int kc = 0; kc < 8; ++kc) {
        bf16x8 aF = *(const bf16x8*)(arow + kc * 32);
#pragma unroll
        for (int t = 0; t < 4; ++t) {
            bf16x8 bF = *(const bf16x8*)(WqkvT + (n0 + t * 16 + l16) * 256 + kc * 32 + quad * 8);
            acc[t] = __builtin_amdgcn_mfma_f32_16x16x32_bf16(aF, bF, acc[t], 0, 0, 0);
        }
    }
#pragma unroll
    for (int t = 0; t < 4; ++t) {
        const int cbase = n0 + t * 16;        // wave-uniform; never straddles a section/head
        const int sect = cbase >> 8;          // 0=q 1=k 2=v
        const int h = (cbase & 255) >> 5;
        const int d = (cbase & 31) + l16;
        const int m = m0 + wid * 16 + quad * 4;
        const int b = m >> 11;
        const int n = m & 2047;
        const int bh = b * 8 + h;
        if (sect == 0) {
            const float bw = rwb[h * 32 + d];
            const float br = rrb[h * 32 + d];
#pragma unroll
            for (int rr = 0; rr < 4; ++rr) {
                int idx = (bh * 2048 + n + rr) * 32 + d;
                q1w[idx] = f2b((acc[t][rr] + bw) * CS);
                q2w[idx] = f2b((acc[t][rr] + br) * CS);
            }
        } else if (sect == 1) {
#pragma unroll
            for (int rr = 0; rr < 4; ++rr)
                kw[(bh * 2048 + n + rr) * 32 + d] = f2b(acc[t][rr]);
        } else {
            ushort4 u;
            u.x = f2b(acc[t][0]); u.y = f2b(acc[t][1]);
            u.z = f2b(acc[t][2]); u.w = f2b(acc[t][3]);
            *(ushort4*)(vTw + (bh * 32 + d) * 2048 + n) = u;   // n is 4-aligned
        }
    }
}

// ---------------------------------------------------------------------------
// [Mx256] @ [256x256] bf16 GEMM, bf16 output (internal: r@Wr).
__global__ __launch_bounds__(256) void kgemm256b(
    const unsigned short* __restrict__ A, const unsigned short* __restrict__ BT,
    unsigned short* __restrict__ C)
{
    const int m0 = blockIdx.x * 64;
    const int n0 = blockIdx.y * 64;
    const int tid = threadIdx.x;
    const int wid = tid >> 6, lane = tid & 63;
    const int l16 = lane & 15, quad = lane >> 4;

    f32x4 acc[4] = {};
    const unsigned short* arow = A + (m0 + wid * 16 + l16) * 256 + quad * 8;
    for (int kc = 0; kc < 8; ++kc) {
        bf16x8 aF = *(const bf16x8*)(arow + kc * 32);
#pragma unroll
        for (int t = 0; t < 4; ++t) {
            bf16x8 bF = *(const bf16x8*)(BT + (n0 + t * 16 + l16) * 256 + kc * 32 + quad * 8);
            acc[t] = __builtin_amdgcn_mfma_f32_16x16x32_bf16(aF, bF, acc[t], 0, 0, 0);
        }
    }
#pragma unroll
    for (int t = 0; t < 4; ++t) {
        const int c = n0 + t * 16 + l16;
        const int m = m0 + wid * 16 + quad * 4;
#pragma unroll
        for (int rr = 0; rr < 4; ++rr)
            C[(m + rr) * 256 + c] = f2b(acc[t][rr]);
    }
}

// ---------------------------------------------------------------------------
// [Mx256] @ [256x256] bf16 GEMM, FLOAT32 output (final: ctx@Wout -> d_out).
__global__ __launch_bounds__(256) void kgemm256f(
    const unsigned short* __restrict__ A, const unsigned short* __restrict__ BT,
    float* __restrict__ C)
{
    const int m0 = blockIdx.x * 64;
    const int n0 = blockIdx.y * 64;
    const int tid = threadIdx.x;
    const int wid = tid >> 6, lane = tid & 63;
    const int l16 = lane & 15, quad = lane >> 4;

    f32x4 acc[4] = {};
    const unsigned short* arow = A + (m0 + wid * 16 + l16) * 256 + quad * 8;
    for (int kc = 0; kc < 8; ++kc) {
        bf16x8 aF = *(const bf16x8*)(arow + kc * 32);
#pragma unroll
        for (int t = 0; t < 4; ++t) {
            bf16x8 bF = *(const bf16x8*)(BT + (n0 + t * 16 + l16) * 256 + kc * 32 + quad * 8);
            acc[t] = __builtin_amdgcn_mfma_f32_16x16x32_bf16(aF, bF, acc[t], 0, 0, 0);
        }
    }
#pragma unroll
    for (int t = 0; t < 4; ++t) {
        const int c = n0 + t * 16 + l16;
        const int m = m0 + wid * 16 + quad * 4;
#pragma unroll
        for (int rr = 0; rr < 4; ++rr)
            C[(m + rr) * 256 + c] = acc[t][rr];
    }
}

// ---------------------------------------------------------------------------
// kattn1: softmax denominators + PV context. NO attn stores. (R11-validated.)
// Block = 4 indep waves; wave owns 16 rows, sweeps all 2048 j.
// Mask staged once to LDS as f32; p = exp2(s)*mjf (multiply, no global loads
// in the chain). Fully-masked rows: p=1 forall j -> l=2048.
// Writes invl[bh][2048] f32 to workspace; ctx bf16.
__global__ __launch_bounds__(256, 4) void kattn1(
    const unsigned short* __restrict__ q1w,  // [32][2048][32]
    const unsigned short* __restrict__ q2w,
    const unsigned short* __restrict__ kw,   // [32][2048][32]
    const unsigned short* __restrict__ vTw,  // [32][32][2048]
    const unsigned short* __restrict__ rr,   // flat [8][2048][32]
    const float* __restrict__ mwf,           // [4][2048] f32 0/1
    float* __restrict__ invl_ws,             // [32][2048] f32
    unsigned short* __restrict__ ctx)        // [4][2048][256] bf16
{
    __shared__ __align__(16) unsigned short pbuf[4][2][16][72];  // 18.4 KB
    __shared__ __align__(16) float msk[2048];                    // 8 KB

    // bh-clustered XCD swizzle (bijective: blk = (blk&7) + 8*idx)
    const int blk = blockIdx.x;              // 1024 = 32 bh * 32 i-tiles
    const int idx = blk >> 3;
    const int bh = ((blk & 7) << 2) | (idx >> 5);
    const int it = idx & 31;
    const int b = bh >> 3, h = bh & 7;
    const int tid = threadIdx.x;
    const int wid = tid >> 6, lane = tid & 63;
    const int l16 = lane & 15, quad = lane >> 4;
    const int i0 = it * 64 + wid * 16;

    // stage mask row for this batch (2048 f32): 256 threads x 8
    {
        const float* src = mwf + b * 2048 + tid * 8;
        *(f32x4*)&msk[tid * 8]     = *(const f32x4*)(src);
        *(f32x4*)&msk[tid * 8 + 4] = *(const f32x4*)(src + 4);
    }
    __syncthreads();

    const bf16x8 a1 = *(const bf16x8*)(q1w + (bh * 2048 + i0 + l16) * 32 + quad * 8);
    const bf16x8 a2 = *(const bf16x8*)(q2w + (bh * 2048 + i0 + l16) * 32 + quad * 8);

    float mi[4];
#pragma unroll
    for (int r = 0; r < 4; ++r)
        mi[r] = msk[i0 + quad * 4 + r];

    const unsigned short* kbase = kw + bh * 2048 * 32;
    const unsigned short* rbase = rr + h * 65536;
    const unsigned short* vbase = vTw + bh * 32 * 2048;

    float lsum[4] = {0.f, 0.f, 0.f, 0.f};
    f32x4 oacc[2] = {};

    for (int jt = 0; jt < 32; ++jt) {
        const int j0 = jt * 64;
        unsigned short (*pb)[72] = pbuf[wid][jt & 1];
        f32x4 s[4];
#pragma unroll
        for (int t = 0; t < 4; ++t) {
            bf16x8 bK = *(const bf16x8*)(kbase + (j0 + t * 16 + l16) * 32 + quad * 8);
            bf16x8 bR = *(const bf16x8*)(rbase + (j0 + t * 16 + l16) * 32 + quad * 8);
            f32x4 z = {};
            z = __builtin_amdgcn_mfma_f32_16x16x32_bf16(a1, bK, z, 0, 0, 0);
            s[t] = __builtin_amdgcn_mfma_f32_16x16x32_bf16(a2, bR, z, 0, 0, 0);
        }
#pragma unroll
        for (int t = 0; t < 4; ++t) {
            const float mj = msk[j0 + t * 16 + l16];
#pragma unroll
            for (int r = 0; r < 4; ++r) {
                float p = (mi[r] == 0.f) ? 1.f : exp2_fast(s[t][r]) * mj;
                lsum[r] += p;
                pb[quad * 4 + r][t * 16 + l16] = f2b(p);
            }
        }
        // Cross-lane dep: lanes read rows other lanes wrote. One ordering
        // point per tile (double buffer covers the WAR side).
        asm volatile("s_waitcnt lgkmcnt(0)" ::: "memory");
#pragma unroll
        for (int kc = 0; kc < 2; ++kc) {
            bf16x8 pA = *(const bf16x8*)(&pb[l16][kc * 32 + quad * 8]);
#pragma unroll
            for (int dt = 0; dt < 2; ++dt) {
                bf16x8 bV = *(const bf16x8*)(vbase + (dt * 16 + l16) * 2048 + j0 + kc * 32 + quad * 8);
                oacc[dt] = __builtin_amdgcn_mfma_f32_16x16x32_bf16(pA, bV, oacc[dt], 0, 0, 0);
            }
        }
    }

    // finalize l: sum across the 16 lanes of each quad-group
    float invl[4];
#pragma unroll
    for (int r = 0; r < 4; ++r) {
        float v = lsum[r];
        v += __shfl_xor(v, 1);
        v += __shfl_xor(v, 2);
        v += __shfl_xor(v, 4);
        v += __shfl_xor(v, 8);
        invl[r] = 1.0f / v;
    }

    // write invl for kattn2
    if (l16 == 0) {
#pragma unroll
        for (int r = 0; r < 4; ++r)
            invl_ws[bh * 2048 + i0 + quad * 4 + r] = invl[r];
    }

    // epilogue: O / l -> ctx (bf16 internal)
#pragma unroll
    for (int dt = 0; dt < 2; ++dt)
#pragma unroll
        for (int r = 0; r < 4; ++r) {
            float o = oacc[dt][r] * invl[r];
            ctx[(b * 2048 + i0 + quad * 4 + r) * 256 + h * 32 + dt * 16 + l16] = f2b(o);
        }
}

// ---------------------------------------------------------------------------
// kattn2: pure streaming attn writer. Recompute scores, scale by invl, store.
// Grid 2048 blocks = (bh, i-tile 64, j-half 1024); 4 waves x 16 rows x 16 jt.
// No LDS cross-lane dep, no barriers -> compiler pipelines freely.
// 8192 waves = 100% occupancy (launch_bounds(256,8); lean body << 64 VGPR).
__global__ __launch_bounds__(256, 8) void kattn2(
    const unsigned short* __restrict__ q1w,  // [32][2048][32]
    const unsigned short* __restrict__ q2w,
    const unsigned short* __restrict__ kw,   // [32][2048][32]
    const unsigned short* __restrict__ rr,   // flat [8][2048][32]
    const float* __restrict__ mwf,           // [4][2048] f32 0/1
    const float* __restrict__ invl_ws,       // [32][2048] f32
    float* __restrict__ attn)                // [32][2048][2048] f32
{
    __shared__ __align__(16) float msk[1024];   // 4 KB (j-half mask)

    // bh-clustered XCD swizzle: XCD x owns bh 4x..4x+3 (256 blocks each)
    const int blk = blockIdx.x;              // 2048 = 32 bh * 32 it * 2 jh
    const int idx = blk >> 3;                // [0,256)
    const int bh = ((blk & 7) << 2) | (idx >> 6);
    const int rem = idx & 63;
    const int it = rem >> 1, jh = rem & 1;
    const int b = bh >> 3, h = bh & 7;
    const int tid = threadIdx.x;
    const int wid = tid >> 6, lane = tid & 63;
    const int l16 = lane & 15, quad = lane >> 4;
    const int i0 = it * 64 + wid * 16;
    const int jbase = jh * 1024;

    // stage j-half mask: 256 threads x 4
    *(f32x4*)&msk[tid * 4] = *(const f32x4*)(mwf + b * 2048 + jbase + tid * 4);
    __syncthreads();

    const bf16x8 a1 = *(const bf16x8*)(q1w + (bh * 2048 + i0 + l16) * 32 + quad * 8);
    const bf16x8 a2 = *(const bf16x8*)(q2w + (bh * 2048 + i0 + l16) * 32 + quad * 8);

    float scl[4], add[4];
#pragma unroll
    for (int r = 0; r < 4; ++r) {
        const int row = i0 + quad * 4 + r;
        const float iv = invl_ws[bh * 2048 + row];
        const float mi = mwf[b * 2048 + row];
        scl[r] = (mi == 0.f) ? 0.f : iv;   // v = exp2(s)*mj*scl + add
        add[r] = (mi == 0.f) ? iv  : 0.f;  // masked row -> uniform invl (=1/2048)
    }

    const unsigned short* kbase = kw + bh * 2048 * 32;
    const unsigned short* rbase = rr + h * 65536;
    float* abase = attn + (bh * 2048 + i0) * 2048;

    for (int jt = 0; jt < 16; ++jt) {
        const int jl = jt * 64;              // offset within j-half
        const int j0 = jbase + jl;           // global j
        f32x4 s[4];
#pragma unroll
        for (int t = 0; t < 4; ++t) {
            bf16x8 bK = *(const bf16x8*)(kbase + (j0 + t * 16 + l16) * 32 + quad * 8);
            bf16x8 bR = *(const bf16x8*)(rbase + (j0 + t * 16 + l16) * 32 + quad * 8);
            f32x4 z = {};
            z = __builtin_amdgcn_mfma_f32_16x16x32_bf16(a1, bK, z, 0, 0, 0);
            s[t] = __builtin_amdgcn_mfma_f32_16x16x32_bf16(a2, bR, z, 0, 0, 0);
        }
#pragma unroll
        for (int t = 0; t < 4; ++t) {
            const float mj = msk[jl + t * 16 + l16];
            float* dst = abase + j0 + t * 16 + l16 + (quad * 4) * 2048;
#pragma unroll
            for (int r = 0; r < 4; ++r) {
                float v = exp2_fast(s[t][r]) * mj * scl[r] + add[r];
                dst[r * 2048] = v;
            }
        }
    }
}

// ---------------------------------------------------------------------------
extern "C" void kernel_launch(void* const* d_in, const int* in_sizes, int n_in,
                              void* d_out, int out_size, void* d_ws, size_t ws_size,
                              hipStream_t stream) {
    const float* w    = (const float*)d_in[0];  // [4][2048][256]
    const float* r    = (const float*)d_in[1];  // [2048][256]
    const int*   am   = (const int*)d_in[2];    // [4][2047]
    const float* Wqkv = (const float*)d_in[3];  // [256][768]
    const float* Wr   = (const float*)d_in[4];  // [256][256]
    const float* Wout = (const float*)d_in[5];  // [256][256]
    const float* rwb  = (const float*)d_in[6];  // [8][1][32]
    const float* rrb  = (const float*)d_in[7];  // [8][1][32]

    float* out  = (float*)d_out;                // [4][2048][256] f32
    float* attn = out + 4 * 2048 * 256;         // [4][8][2048][2048] f32

    unsigned short* ws    = (unsigned short*)d_ws;          // ~27 MB scratch
    unsigned short* wb    = ws;                             // 2,097,152
    unsigned short* rb    = wb + 2097152;                   // 524,288
    unsigned short* q1w   = rb + 524288;                    // 2,097,152
    unsigned short* q2w   = q1w + 2097152;
    unsigned short* kw    = q2w + 2097152;
    unsigned short* vTw   = kw + 2097152;
    unsigned short* rrw   = vTw + 2097152;                  // 524,288
    unsigned short* ctx   = rrw + 524288;                   // 2,097,152
    unsigned short* WqkvT = ctx + 2097152;                  // 196,608
    unsigned short* WrT   = WqkvT + 196608;                 // 65,536
    unsigned short* WoutT = WrT + 65536;                    // 65,536
    float*          mwfp  = (float*)(WoutT + 65536);        // 8,192 f32 (32 KB)
    float*          invlp = mwfp + 8192;                    // 65,536 f32 (256 KB)

    kprep    <<<dim3(11552),   dim3(256), 0, stream>>>(w, r, Wqkv, Wr, Wout, am,
                                                       wb, rb, WqkvT, WrT, WoutT, mwfp);
    kqkv     <<<dim3(128, 12), dim3(256), 0, stream>>>(wb, WqkvT, rwb, rrb, q1w, q2w, kw, vTw);
    kgemm256b<<<dim3(32, 4),   dim3(256), 0, stream>>>(rb, WrT, rrw);
    kattn1   <<<dim3(1024),    dim3(256), 0, stream>>>(q1w, q2w, kw, vTw, rrw, mwfp, invlp, ctx);
    kattn2   <<<dim3(2048),    dim3(256), 0, stream>>>(q1w, q2w, kw, rrw, mwfp, invlp, attn);
    kgemm256f<<<dim3(128, 4),  dim3(256), 0, stream>>>(ctx, WoutT, out);
}